// Round 4
// baseline (218.547 us; speedup 1.0000x reference)
//
#include <hip/hip_runtime.h>
#include <hip/hip_bf16.h>
#include <math.h>

// Problem constants (BN, N, FIN, FO, H) from the reference
#define BN_   4
#define NN_   2048
#define FIN_  128
#define FO_   64
#define H_    4
#define D_    256   // FO*H

typedef __attribute__((ext_vector_type(8))) short bf16x8;   // 8 bf16 = 4 VGPRs
typedef __attribute__((ext_vector_type(4))) float floatx4;  // MFMA C/D frag

__device__ __forceinline__ float bf2f(short u) {
    union { unsigned int i; float f; } v;
    v.i = ((unsigned int)(unsigned short)u) << 16;
    return v.f;
}
__device__ __forceinline__ short f2bf(float f) {
    union { float f; unsigned int u; } v; v.f = f;
    unsigned int r = v.u + 0x7fffu + ((v.u >> 16) & 1u);  // RNE
    return (short)(unsigned short)(r >> 16);
}
// load 8 consecutive fp32 and round to a bf16x8 MFMA fragment
__device__ __forceinline__ bf16x8 load8f(const float* __restrict__ p) {
    floatx4 a = *(const floatx4*)p;
    floatx4 b = *(const floatx4*)(p + 4);
    bf16x8 r;
    r[0] = f2bf(a[0]); r[1] = f2bf(a[1]); r[2] = f2bf(a[2]); r[3] = f2bf(a[3]);
    r[4] = f2bf(b[0]); r[5] = f2bf(b[1]); r[6] = f2bf(b[2]); r[7] = f2bf(b[3]);
    return r;
}

// ---------------------------------------------------------------------------
// Kernel 1: PT[b_rel][h][f][j] = sum_c x[b,j,c] * W_proj[f*H+h, c]  (bf16)
// PT slab per batch: index (b_rel*D_ + (h*64+f))*NN_ + j  (j contiguous).
// MFMA 16x16x32 bf16: A[m=lane&15][k=quad*8+e]=W rows, B[n=lane&15][k]=x.
// ---------------------------------------------------------------------------
__global__ __launch_bounds__(256) void proj_kernel(
    const float* __restrict__ x,      // (BN, NN, FIN) fp32
    const float* __restrict__ wproj,  // (D, FIN) fp32
    short* __restrict__ pt,           // (nb*D, NN) bf16 slabs
    int b0)
{
    const int tid  = threadIdx.x;
    const int wave = tid >> 6;
    const int lane = tid & 63;
    const int l16  = lane & 15;
    const int quad = lane >> 4;

    const int b_rel = blockIdx.z;
    const int b  = b0 + b_rel;
    const int d0 = blockIdx.y * 64;
    const int j0 = blockIdx.x * 256 + wave * 64;

    floatx4 acc[4][4];
#pragma unroll
    for (int mi = 0; mi < 4; ++mi)
#pragma unroll
        for (int nj = 0; nj < 4; ++nj)
            acc[mi][nj] = (floatx4){0.f, 0.f, 0.f, 0.f};

#pragma unroll
    for (int kc = 0; kc < 4; ++kc) {
        const int c = kc * 32 + quad * 8;
        bf16x8 afr[4], bfr[4];
#pragma unroll
        for (int mi = 0; mi < 4; ++mi) {
            int dp = d0 + mi * 16 + l16;          // d' = h*64 + f
            int f  = dp & 63;
            int hh = dp >> 6;
            int srow = f * H_ + hh;               // W_proj row (flat d = f*H+h)
            afr[mi] = load8f(wproj + srow * FIN_ + c);
        }
#pragma unroll
        for (int nj = 0; nj < 4; ++nj) {
            int j = j0 + nj * 16 + l16;
            bfr[nj] = load8f(x + ((size_t)b * NN_ + j) * FIN_ + c);
        }
#pragma unroll
        for (int mi = 0; mi < 4; ++mi)
#pragma unroll
            for (int nj = 0; nj < 4; ++nj)
                acc[mi][nj] = __builtin_amdgcn_mfma_f32_16x16x32_bf16(
                    afr[mi], bfr[nj], acc[mi][nj], 0, 0, 0);
    }

    // C/D layout: col(n=j) = lane&15, row(m=d') = quad*4 + reg
#pragma unroll
    for (int mi = 0; mi < 4; ++mi) {
#pragma unroll
        for (int r = 0; r < 4; ++r) {
            int dp = d0 + mi * 16 + quad * 4 + r;
            size_t base = ((size_t)b_rel * D_ + dp) * NN_;
#pragma unroll
            for (int nj = 0; nj < 4; ++nj) {
                int j = j0 + nj * 16 + l16;
                pt[base + j] = f2bf(acc[mi][nj][r]);
            }
        }
    }
}

// ---------------------------------------------------------------------------
// Kernel 1b: s_src[b,h,n] = sum_f PT[b_rel][h][f][n] * score_src[h,f] (+tgt)
// ---------------------------------------------------------------------------
__global__ __launch_bounds__(256) void score_kernel(
    const short* __restrict__ pt,     // (nb*D, NN) bf16
    const float* __restrict__ ssrc,   // (H, FO) fp32
    const float* __restrict__ stgt,   // (H, FO) fp32
    float* __restrict__ s_src,        // (BN*H, NN) fp32 (absolute index)
    float* __restrict__ s_tgt,
    int b0)
{
    const int tid   = threadIdx.x;
    const int yy    = blockIdx.y;         // b_rel*H + h
    const int h     = yy & (H_ - 1);
    const int b_rel = yy >> 2;
    const int b     = b0 + b_rel;
    const int n     = blockIdx.x * 256 + tid;
    const short* base = pt + ((size_t)b_rel * D_ + h * FO_) * NN_ + n;
    float as = 0.f, at = 0.f;
#pragma unroll 8
    for (int f = 0; f < FO_; ++f) {
        float v = bf2f(base[(size_t)f * NN_]);
        as += v * ssrc[h * FO_ + f];
        at += v * stgt[h * FO_ + f];
    }
    s_src[((size_t)b * H_ + h) * NN_ + n] = as;
    s_tgt[((size_t)b * H_ + h) * NN_ + n] = at;
}

// ---------------------------------------------------------------------------
// Kernel 2: fused attention. One wave = one head x 16 i-rows; block = 4 waves
// sharing the same adj rows (L1 reuse). Max-free softmax (scores bounded):
// w = exp(score), l = sum(w), O = (W @ P)/l. Weights built directly in MFMA
// A-layout from contiguous 32B fp32 adj loads. No LDS, no barriers.
// Output is fp32 (reference returns float32).
// ---------------------------------------------------------------------------
__global__ __launch_bounds__(256) void attn_kernel(
    const float* __restrict__ adj,    // (BN, NN, NN) fp32
    const short* __restrict__ pt,     // (nb*D, NN) bf16
    const float* __restrict__ s_src,  // (BN*H, NN)
    const float* __restrict__ s_tgt,
    const float* __restrict__ bias,   // (D,) fp32
    float* __restrict__ out,          // (BN, NN, D) fp32
    int b0)
{
    const int tid  = threadIdx.x;
    const int h    = tid >> 6;        // wave index = head
    const int lane = tid & 63;
    const int l16  = lane & 15;
    const int quad = lane >> 4;

    const int b_rel = blockIdx.y;
    const int b  = b0 + b_rel;
    const int i0 = blockIdx.x * 16;
    const int bh = b * H_ + h;

    const float ssrc0 = s_src[(size_t)bh * NN_ + i0 + l16];

    const float* adj_row = adj + ((size_t)b * NN_ + i0 + l16) * NN_;
    const short* pt_bh   = pt + ((size_t)b_rel * D_ + h * FO_) * NN_;
    const float* stgt_bh = s_tgt + (size_t)bh * NN_;

    floatx4 acc[4];
#pragma unroll
    for (int nj = 0; nj < 4; ++nj)
        acc[nj] = (floatx4){0.f, 0.f, 0.f, 0.f};
    float lsum = 0.f;

    for (int jt = 0; jt < NN_ / 32; ++jt) {
        const int jq = jt * 32 + quad * 8;    // this lane's 8 j's
        floatx4 st0 = *(const floatx4*)(stgt_bh + jq);
        floatx4 st1 = *(const floatx4*)(stgt_bh + jq + 4);
        floatx4 aj0 = *(const floatx4*)(adj_row + jq);
        floatx4 aj1 = *(const floatx4*)(adj_row + jq + 4);
        bf16x8 bfr[4];
#pragma unroll
        for (int nj = 0; nj < 4; ++nj)
            bfr[nj] = *(const bf16x8*)(pt_bh + (size_t)(nj * 16 + l16) * NN_ + jq);

        bf16x8 a0;
#pragma unroll
        for (int e = 0; e < 8; ++e) {
            float stv = (e < 4) ? st0[e] : st1[e - 4];
            float av  = (e < 4) ? aj0[e] : aj1[e - 4];
            float s = ssrc0 + stv;
            s = fmaxf(s, 0.2f * s);               // leaky_relu(0.2)
            s += av;
            float w = __expf(s);
            short wb = f2bf(w);
            a0[e] = wb;
            lsum += bf2f(wb);                      // sum the ROUNDED weights
        }
#pragma unroll
        for (int nj = 0; nj < 4; ++nj)
            acc[nj] = __builtin_amdgcn_mfma_f32_16x16x32_bf16(a0, bfr[nj], acc[nj], 0, 0, 0);
    }

    // row-sums: lanes {l16, l16+16, l16+32, l16+48} hold quad-partials
    lsum += __shfl_xor(lsum, 16, 64);
    lsum += __shfl_xor(lsum, 32, 64);

    // epilogue: C/D layout row = quad*4+r, col = nj*16+l16
#pragma unroll
    for (int r = 0; r < 4; ++r) {
        int srcl = quad * 4 + r;                  // lane whose l16 == row
        float l = __shfl(lsum, srcl, 64);
        float linv = 1.0f / l;
        int i = i0 + quad * 4 + r;
#pragma unroll
        for (int nj = 0; nj < 4; ++nj) {
            int col = h * FO_ + nj * 16 + l16;
            float v = acc[nj][r] * linv + bias[col];
            v = (v > 0.f) ? v : expm1f(v);        // elu (fp32 out)
            out[((size_t)b * NN_ + i) * D_ + col] = v;
        }
    }
}

// ---------------------------------------------------------------------------
extern "C" void kernel_launch(void* const* d_in, const int* in_sizes, int n_in,
                              void* d_out, int out_size, void* d_ws, size_t ws_size,
                              hipStream_t stream) {
    const float* x     = (const float*)d_in[0];   // (4,2048,128) fp32
    const float* adj   = (const float*)d_in[1];   // (4,2048,2048) fp32
    const float* wproj = (const float*)d_in[2];   // (256,128) fp32
    const float* ssrc  = (const float*)d_in[3];   // (4,64) fp32
    const float* stgt  = (const float*)d_in[4];   // (4,64) fp32
    const float* bias  = (const float*)d_in[5];   // (256,) fp32
    float* out = (float*)d_out;                   // (4,2048,256) fp32

    // ws layout: s_src (128 KiB) | s_tgt (128 KiB) | PT slabs (1 MiB per batch)
    const size_t SB   = (size_t)BN_ * H_ * NN_ * 4;   // 131072 B
    const size_t SLAB = (size_t)D_ * NN_ * 2;          // 1 MiB per batch
    float* s_src = (float*)d_ws;
    float* s_tgt = (float*)((char*)d_ws + SB);
    short* pt    = (short*)((char*)d_ws + 2 * SB);

    // batch-slice PT so total ws usage fits ws_size (nb constant per session)
    int nb;
    if (ws_size >= 2 * SB + 4 * SLAB) nb = 4;
    else {
        size_t avail = (ws_size > 2 * SB) ? (ws_size - 2 * SB) / SLAB : 0;
        nb = (int)avail; if (nb < 1) nb = 1; if (nb > 4) nb = 4;
    }

    for (int bb0 = 0; bb0 < BN_; bb0 += nb) {
        int cnt = (BN_ - bb0 < nb) ? (BN_ - bb0) : nb;
        proj_kernel<<<dim3(NN_ / 256, D_ / 64, cnt), 256, 0, stream>>>(x, wproj, pt, bb0);
        score_kernel<<<dim3(NN_ / 256, H_ * cnt), 256, 0, stream>>>(pt, ssrc, stgt, s_src, s_tgt, bb0);
        attn_kernel<<<dim3(NN_ / 16, cnt), 256, 0, stream>>>(adj, pt, s_src, s_tgt, bias, out, bb0);
    }
}

// Round 5
// 215.024 us; speedup vs baseline: 1.0164x; 1.0164x over previous
//
#include <hip/hip_runtime.h>
#include <hip/hip_bf16.h>
#include <math.h>

// Problem constants (BN, N, FIN, FO, H) from the reference
#define BN_   4
#define NN_   2048
#define FIN_  128
#define FO_   64
#define H_    4
#define D_    256   // FO*H

typedef __attribute__((ext_vector_type(8))) short bf16x8;   // 8 bf16 = 4 VGPRs
typedef __attribute__((ext_vector_type(4))) float floatx4;  // MFMA C/D frag

__device__ __forceinline__ float bf2f(short u) {
    union { unsigned int i; float f; } v;
    v.i = ((unsigned int)(unsigned short)u) << 16;
    return v.f;
}
__device__ __forceinline__ short f2bf(float f) {
    union { float f; unsigned int u; } v; v.f = f;
    unsigned int r = v.u + 0x7fffu + ((v.u >> 16) & 1u);  // RNE
    return (short)(unsigned short)(r >> 16);
}
// load 8 consecutive fp32 and round to a bf16x8 MFMA fragment
__device__ __forceinline__ bf16x8 load8f(const float* __restrict__ p) {
    floatx4 a = *(const floatx4*)p;
    floatx4 b = *(const floatx4*)(p + 4);
    bf16x8 r;
    r[0] = f2bf(a[0]); r[1] = f2bf(a[1]); r[2] = f2bf(a[2]); r[3] = f2bf(a[3]);
    r[4] = f2bf(b[0]); r[5] = f2bf(b[1]); r[6] = f2bf(b[2]); r[7] = f2bf(b[3]);
    return r;
}

// ---------------------------------------------------------------------------
// Kernel 1: PT[b_rel][h][f][j] = sum_c x[b,j,c] * W_proj[f*H+h, c]  (bf16)
// + fused score epilogue: s_src[b,h,j] = sum_f PT*score_src[h,f] (and tgt),
// computed from the fp32 accumulators (block d0 = one full head).
// MFMA 16x16x32 bf16: A[m=lane&15][k=quad*8+e]=W rows, B[n=lane&15][k]=x.
// ---------------------------------------------------------------------------
__global__ __launch_bounds__(256) void proj_kernel(
    const float* __restrict__ x,      // (BN, NN, FIN) fp32
    const float* __restrict__ wproj,  // (D, FIN) fp32
    const float* __restrict__ ssrc,   // (H, FO) fp32
    const float* __restrict__ stgt,   // (H, FO) fp32
    short* __restrict__ pt,           // (nb*D, NN) bf16 slabs
    float* __restrict__ s_src,        // (BN*H, NN) fp32 (absolute index)
    float* __restrict__ s_tgt,
    int b0)
{
    const int tid  = threadIdx.x;
    const int wave = tid >> 6;
    const int lane = tid & 63;
    const int l16  = lane & 15;
    const int quad = lane >> 4;

    const int b_rel = blockIdx.z;
    const int b  = b0 + b_rel;
    const int h  = blockIdx.y;            // D_/64 == H_, so y-block == head
    const int d0 = h * 64;
    const int j0 = blockIdx.x * 256 + wave * 64;

    floatx4 acc[4][4];
#pragma unroll
    for (int mi = 0; mi < 4; ++mi)
#pragma unroll
        for (int nj = 0; nj < 4; ++nj)
            acc[mi][nj] = (floatx4){0.f, 0.f, 0.f, 0.f};

#pragma unroll
    for (int kc = 0; kc < 4; ++kc) {
        const int c = kc * 32 + quad * 8;
        bf16x8 afr[4], bfr[4];
#pragma unroll
        for (int mi = 0; mi < 4; ++mi) {
            int dp = d0 + mi * 16 + l16;          // d' = h*64 + f
            int f  = dp & 63;
            int srow = f * H_ + h;                // W_proj row (flat d = f*H+h)
            afr[mi] = load8f(wproj + srow * FIN_ + c);
        }
#pragma unroll
        for (int nj = 0; nj < 4; ++nj) {
            int j = j0 + nj * 16 + l16;
            bfr[nj] = load8f(x + ((size_t)b * NN_ + j) * FIN_ + c);
        }
#pragma unroll
        for (int mi = 0; mi < 4; ++mi)
#pragma unroll
            for (int nj = 0; nj < 4; ++nj)
                acc[mi][nj] = __builtin_amdgcn_mfma_f32_16x16x32_bf16(
                    afr[mi], bfr[nj], acc[mi][nj], 0, 0, 0);
    }

    // C/D layout: col(n=j) = lane&15, row(m=d') = quad*4 + reg
#pragma unroll
    for (int mi = 0; mi < 4; ++mi) {
#pragma unroll
        for (int r = 0; r < 4; ++r) {
            int dp = d0 + mi * 16 + quad * 4 + r;
            size_t base = ((size_t)b_rel * D_ + dp) * NN_;
#pragma unroll
            for (int nj = 0; nj < 4; ++nj) {
                int j = j0 + nj * 16 + l16;
                pt[base + j] = f2bf(acc[mi][nj][r]);
            }
        }
    }

    // fused score: this lane holds rows f = mi*16 + quad*4 + r (all 64 f
    // across the 4 quads), cols j = nj*16 + l16.
    float wsc[4][4], wtg[4][4];
#pragma unroll
    for (int mi = 0; mi < 4; ++mi)
#pragma unroll
        for (int r = 0; r < 4; ++r) {
            int f = mi * 16 + quad * 4 + r;
            wsc[mi][r] = ssrc[h * FO_ + f];
            wtg[mi][r] = stgt[h * FO_ + f];
        }
#pragma unroll
    for (int nj = 0; nj < 4; ++nj) {
        float ps = 0.f, ptg = 0.f;
#pragma unroll
        for (int mi = 0; mi < 4; ++mi)
#pragma unroll
            for (int r = 0; r < 4; ++r) {
                float v = acc[mi][nj][r];
                ps  += wsc[mi][r] * v;
                ptg += wtg[mi][r] * v;
            }
        ps  += __shfl_xor(ps, 16, 64);  ps  += __shfl_xor(ps, 32, 64);
        ptg += __shfl_xor(ptg, 16, 64); ptg += __shfl_xor(ptg, 32, 64);
        if (quad == 0) {
            int j = j0 + nj * 16 + l16;
            s_src[((size_t)b * H_ + h) * NN_ + j] = ps;
            s_tgt[((size_t)b * H_ + h) * NN_ + j] = ptg;
        }
    }
}

// ---------------------------------------------------------------------------
// Kernel 2: fused attention. Block = 512 threads = 8 waves, all on the SAME
// (b, head, 16-row i-tile); waves split the j-loop (256 j each) and combine
// partial (O, lsum) via one LDS reduction. Max-free softmax (scores bounded):
// w = exp(score), l = sum(w), O = (W @ P)/l. Weights built directly in MFMA
// A-layout from contiguous 32B fp32 adj loads. Output fp32.
// ---------------------------------------------------------------------------
#define RSTRIDE 65   // LDS row stride (pad +1 col to break bank alignment)
#define WSLOT   (RSTRIDE * 16 + 16)   // 1056 floats per wave slot

__global__ __launch_bounds__(512) void attn_kernel(
    const float* __restrict__ adj,    // (BN, NN, NN) fp32
    const short* __restrict__ pt,     // (nb*D, NN) bf16
    const float* __restrict__ s_src,  // (BN*H, NN)
    const float* __restrict__ s_tgt,
    const float* __restrict__ bias,   // (D,) fp32
    float* __restrict__ out,          // (BN, NN, D) fp32
    int b0)
{
    __shared__ float red[8][WSLOT];   // 33792 B

    const int tid  = threadIdx.x;
    const int w    = tid >> 6;        // wave = j-slice
    const int lane = tid & 63;
    const int l16  = lane & 15;
    const int quad = lane >> 4;

    const int b_rel = blockIdx.z;
    const int b  = b0 + b_rel;
    const int h  = blockIdx.y;
    const int i0 = blockIdx.x * 16;
    const int bh = b * H_ + h;

    const float ssrc0 = s_src[(size_t)bh * NN_ + i0 + l16];

    const float* adj_row = adj + ((size_t)b * NN_ + i0 + l16) * NN_;
    const short* pt_bh   = pt + ((size_t)b_rel * D_ + h * FO_) * NN_;
    const float* stgt_bh = s_tgt + (size_t)bh * NN_;

    floatx4 acc[4];
#pragma unroll
    for (int nj = 0; nj < 4; ++nj)
        acc[nj] = (floatx4){0.f, 0.f, 0.f, 0.f};
    float lsum = 0.f;

    for (int jt = 0; jt < 8; ++jt) {              // 8 iters x 32 j per wave
        const int jq = w * 256 + jt * 32 + quad * 8;
        floatx4 st0 = *(const floatx4*)(stgt_bh + jq);
        floatx4 st1 = *(const floatx4*)(stgt_bh + jq + 4);
        floatx4 aj0 = *(const floatx4*)(adj_row + jq);
        floatx4 aj1 = *(const floatx4*)(adj_row + jq + 4);
        bf16x8 bfr[4];
#pragma unroll
        for (int nj = 0; nj < 4; ++nj)
            bfr[nj] = *(const bf16x8*)(pt_bh + (size_t)(nj * 16 + l16) * NN_ + jq);

        bf16x8 a0;
#pragma unroll
        for (int e = 0; e < 8; ++e) {
            float stv = (e < 4) ? st0[e] : st1[e - 4];
            float av  = (e < 4) ? aj0[e] : aj1[e - 4];
            float s = ssrc0 + stv;
            s = fmaxf(s, 0.2f * s);               // leaky_relu(0.2)
            s += av;
            float wv = __expf(s);
            short wb = f2bf(wv);
            a0[e] = wb;
            lsum += bf2f(wb);                      // sum the ROUNDED weights
        }
#pragma unroll
        for (int nj = 0; nj < 4; ++nj)
            acc[nj] = __builtin_amdgcn_mfma_f32_16x16x32_bf16(a0, bfr[nj], acc[nj], 0, 0, 0);
    }

    // wave-local row-sum over quads (row = l16 in A-layout)
    lsum += __shfl_xor(lsum, 16, 64);
    lsum += __shfl_xor(lsum, 32, 64);

    // stage 1: dump wave partials to LDS. C/D layout: row=quad*4+r, col=nj*16+l16
#pragma unroll
    for (int nj = 0; nj < 4; ++nj)
#pragma unroll
        for (int r = 0; r < 4; ++r)
            red[w][(quad * 4 + r) * RSTRIDE + nj * 16 + l16] = acc[nj][r];
    if (quad == 0)
        red[w][16 * RSTRIDE + l16] = lsum;
    __syncthreads();

    // stage 2: 512 threads reduce 16x64 elems (2 each) over 8 waves
#pragma unroll
    for (int p = 0; p < 2; ++p) {
        int e   = tid + p * 512;
        int row = e >> 6;
        int col = e & 63;
        float s = 0.f, l = 0.f;
#pragma unroll
        for (int ww = 0; ww < 8; ++ww) {
            s += red[ww][row * RSTRIDE + col];
            l += red[ww][16 * RSTRIDE + row];
        }
        float v = s / l + bias[h * FO_ + col];
        v = (v > 0.f) ? v : expm1f(v);            // elu (fp32 out)
        out[((size_t)b * NN_ + i0 + row) * D_ + h * FO_ + col] = v;
    }
}

// ---------------------------------------------------------------------------
extern "C" void kernel_launch(void* const* d_in, const int* in_sizes, int n_in,
                              void* d_out, int out_size, void* d_ws, size_t ws_size,
                              hipStream_t stream) {
    const float* x     = (const float*)d_in[0];   // (4,2048,128) fp32
    const float* adj   = (const float*)d_in[1];   // (4,2048,2048) fp32
    const float* wproj = (const float*)d_in[2];   // (256,128) fp32
    const float* ssrc  = (const float*)d_in[3];   // (4,64) fp32
    const float* stgt  = (const float*)d_in[4];   // (4,64) fp32
    const float* bias  = (const float*)d_in[5];   // (256,) fp32
    float* out = (float*)d_out;                   // (4,2048,256) fp32

    // ws layout: s_src (128 KiB) | s_tgt (128 KiB) | PT slabs (1 MiB per batch)
    const size_t SB   = (size_t)BN_ * H_ * NN_ * 4;   // 131072 B
    const size_t SLAB = (size_t)D_ * NN_ * 2;          // 1 MiB per batch
    float* s_src = (float*)d_ws;
    float* s_tgt = (float*)((char*)d_ws + SB);
    short* pt    = (short*)((char*)d_ws + 2 * SB);

    // batch-slice PT so total ws usage fits ws_size (nb constant per session)
    int nb;
    if (ws_size >= 2 * SB + 4 * SLAB) nb = 4;
    else {
        size_t avail = (ws_size > 2 * SB) ? (ws_size - 2 * SB) / SLAB : 0;
        nb = (int)avail; if (nb < 1) nb = 1; if (nb > 4) nb = 4;
    }

    for (int bb0 = 0; bb0 < BN_; bb0 += nb) {
        int cnt = (BN_ - bb0 < nb) ? (BN_ - bb0) : nb;
        proj_kernel<<<dim3(NN_ / 256, H_, cnt), 256, 0, stream>>>(
            x, wproj, ssrc, stgt, pt, s_src, s_tgt, bb0);
        attn_kernel<<<dim3(NN_ / 16, H_, cnt), 512, 0, stream>>>(
            adj, pt, s_src, s_tgt, bias, out, bb0);
    }
}

// Round 6
// 211.390 us; speedup vs baseline: 1.0339x; 1.0172x over previous
//
#include <hip/hip_runtime.h>
#include <hip/hip_bf16.h>
#include <math.h>

// Problem constants (BN, N, FIN, FO, H) from the reference
#define BN_   4
#define NN_   2048
#define FIN_  128
#define FO_   64
#define H_    4
#define D_    256   // FO*H

typedef __attribute__((ext_vector_type(8))) short bf16x8;   // 8 bf16 = 4 VGPRs
typedef __attribute__((ext_vector_type(4))) float floatx4;  // MFMA C/D frag
typedef __attribute__((ext_vector_type(2))) float f32x2;    // v_pk_*_f32 pair

#define LOG2E 1.4426950408889634f

#if __has_builtin(__builtin_amdgcn_exp2f)
#define EXP2(x) __builtin_amdgcn_exp2f(x)
#else
#define EXP2(x) exp2f(x)
#endif

__device__ __forceinline__ float bf2f(short u) {
    union { unsigned int i; float f; } v;
    v.i = ((unsigned int)(unsigned short)u) << 16;
    return v.f;
}
__device__ __forceinline__ short f2bf(float f) {
    union { float f; unsigned int u; } v; v.f = f;
    unsigned int r = v.u + 0x7fffu + ((v.u >> 16) & 1u);  // RNE
    return (short)(unsigned short)(r >> 16);
}

// pack two floats to two bf16 (RNE) in one dword; elem0 in low 16 bits
#if defined(__BF16_MANT_DIG__)
typedef __bf16 bfr2 __attribute__((ext_vector_type(2)));
__device__ __forceinline__ unsigned int pack_bf16(float a, float b) {
    union { bfr2 h; unsigned int u; } v;
    v.h = (bfr2){(__bf16)a, (__bf16)b};   // gfx950: v_cvt_pk_bf16_f32
    return v.u;
}
#else
__device__ __forceinline__ unsigned int pack_bf16(float a, float b) {
    return ((unsigned int)(unsigned short)f2bf(a)) |
           (((unsigned int)(unsigned short)f2bf(b)) << 16);
}
#endif

// load 8 consecutive fp32 and round to a bf16x8 MFMA fragment
__device__ __forceinline__ bf16x8 load8f(const float* __restrict__ p) {
    floatx4 a = *(const floatx4*)p;
    floatx4 b = *(const floatx4*)(p + 4);
    union { bf16x8 v; unsigned int u[4]; } r;
    r.u[0] = pack_bf16(a[0], a[1]);
    r.u[1] = pack_bf16(a[2], a[3]);
    r.u[2] = pack_bf16(b[0], b[1]);
    r.u[3] = pack_bf16(b[2], b[3]);
    return r.v;
}

// ---------------------------------------------------------------------------
// Kernel 1: PT[b_rel][h][f][j] = sum_c x[b,j,c] * W_proj[f*H+h, c]  (bf16)
// + fused score epilogue: s_src[b,h,j] = sum_f PT*score_src[h,f] (and tgt).
// MFMA 16x16x32 bf16: A[m=lane&15][k=quad*8+e]=W rows, B[n=lane&15][k]=x.
// ---------------------------------------------------------------------------
__global__ __launch_bounds__(256) void proj_kernel(
    const float* __restrict__ x,      // (BN, NN, FIN) fp32
    const float* __restrict__ wproj,  // (D, FIN) fp32
    const float* __restrict__ ssrc,   // (H, FO) fp32
    const float* __restrict__ stgt,   // (H, FO) fp32
    short* __restrict__ pt,           // (nb*D, NN) bf16 slabs
    float* __restrict__ s_src,        // (BN*H, NN) fp32 (absolute index)
    float* __restrict__ s_tgt,
    int b0)
{
    const int tid  = threadIdx.x;
    const int wave = tid >> 6;
    const int lane = tid & 63;
    const int l16  = lane & 15;
    const int quad = lane >> 4;

    const int b_rel = blockIdx.z;
    const int b  = b0 + b_rel;
    const int h  = blockIdx.y;            // D_/64 == H_, so y-block == head
    const int d0 = h * 64;
    const int j0 = blockIdx.x * 256 + wave * 64;

    floatx4 acc[4][4];
#pragma unroll
    for (int mi = 0; mi < 4; ++mi)
#pragma unroll
        for (int nj = 0; nj < 4; ++nj)
            acc[mi][nj] = (floatx4){0.f, 0.f, 0.f, 0.f};

#pragma unroll
    for (int kc = 0; kc < 4; ++kc) {
        const int c = kc * 32 + quad * 8;
        bf16x8 afr[4], bfr[4];
#pragma unroll
        for (int mi = 0; mi < 4; ++mi) {
            int dp = d0 + mi * 16 + l16;          // d' = h*64 + f
            int f  = dp & 63;
            int srow = f * H_ + h;                // W_proj row (flat d = f*H+h)
            afr[mi] = load8f(wproj + srow * FIN_ + c);
        }
#pragma unroll
        for (int nj = 0; nj < 4; ++nj) {
            int j = j0 + nj * 16 + l16;
            bfr[nj] = load8f(x + ((size_t)b * NN_ + j) * FIN_ + c);
        }
#pragma unroll
        for (int mi = 0; mi < 4; ++mi)
#pragma unroll
            for (int nj = 0; nj < 4; ++nj)
                acc[mi][nj] = __builtin_amdgcn_mfma_f32_16x16x32_bf16(
                    afr[mi], bfr[nj], acc[mi][nj], 0, 0, 0);
    }

    // C/D layout: col(n=j) = lane&15, row(m=d') = quad*4 + reg
#pragma unroll
    for (int mi = 0; mi < 4; ++mi) {
#pragma unroll
        for (int r = 0; r < 4; ++r) {
            int dp = d0 + mi * 16 + quad * 4 + r;
            size_t base = ((size_t)b_rel * D_ + dp) * NN_;
#pragma unroll
            for (int nj = 0; nj < 4; ++nj) {
                int j = j0 + nj * 16 + l16;
                pt[base + j] = f2bf(acc[mi][nj][r]);
            }
        }
    }

    // fused score: lane holds rows f = mi*16 + quad*4 + r, cols j = nj*16+l16
    float wsc[4][4], wtg[4][4];
#pragma unroll
    for (int mi = 0; mi < 4; ++mi)
#pragma unroll
        for (int r = 0; r < 4; ++r) {
            int f = mi * 16 + quad * 4 + r;
            wsc[mi][r] = ssrc[h * FO_ + f];
            wtg[mi][r] = stgt[h * FO_ + f];
        }
#pragma unroll
    for (int nj = 0; nj < 4; ++nj) {
        float ps = 0.f, ptg = 0.f;
#pragma unroll
        for (int mi = 0; mi < 4; ++mi)
#pragma unroll
            for (int r = 0; r < 4; ++r) {
                float v = acc[mi][nj][r];
                ps  += wsc[mi][r] * v;
                ptg += wtg[mi][r] * v;
            }
        ps  += __shfl_xor(ps, 16, 64);  ps  += __shfl_xor(ps, 32, 64);
        ptg += __shfl_xor(ptg, 16, 64); ptg += __shfl_xor(ptg, 32, 64);
        if (quad == 0) {
            int j = j0 + nj * 16 + l16;
            s_src[((size_t)b * H_ + h) * NN_ + j] = ps;
            s_tgt[((size_t)b * H_ + h) * NN_ + j] = ptg;
        }
    }
}

// ---------------------------------------------------------------------------
// Kernel 2: fused attention. Block = 512 threads = 8 waves on the SAME
// (b, head, 16-row i-tile); waves split the j-loop (256 j each), combine
// partial (O, lsum) via one LDS reduction. Max-free softmax (bounded scores):
// w = 2^((leaky(s)+adj)*log2e), l = sum(w), O = (W @ P)/l.
// All loop loads are base+static-immediate (full unroll, bases pre-offset).
// lsum accumulates UNROUNDED w (RNE rounding of MFMA weights is unbiased).
// ---------------------------------------------------------------------------
#define RSTRIDE 65   // LDS row stride (pad +1 col to break bank alignment)
#define WSLOT   (RSTRIDE * 16 + 16)   // 1056 floats per wave slot

__global__ __launch_bounds__(512, 4) void attn_kernel(
    const float* __restrict__ adj,    // (BN, NN, NN) fp32
    const short* __restrict__ pt,     // (nb*D, NN) bf16
    const float* __restrict__ s_src,  // (BN*H, NN)
    const float* __restrict__ s_tgt,
    const float* __restrict__ bias,   // (D,) fp32
    float* __restrict__ out,          // (BN, NN, D) fp32
    int b0)
{
    __shared__ float red[8][WSLOT];   // 33792 B

    const int tid  = threadIdx.x;
    const int w    = tid >> 6;        // wave = j-slice
    const int lane = tid & 63;
    const int l16  = lane & 15;
    const int quad = lane >> 4;
    const int qo   = quad * 8;        // element offset within a 32-j tile

    const int b_rel = blockIdx.z;
    const int b  = b0 + b_rel;
    const int h  = blockIdx.y;
    const int i0 = blockIdx.x * 16;
    const int bh = b * H_ + h;

    const float ssrc0 = s_src[(size_t)bh * NN_ + i0 + l16];
    const f32x2 ssrc2 = (f32x2){ssrc0, ssrc0};

    // pre-offset bases: wave j-slice (w*256) + quad offset folded in
    const float* adjp = adj + ((size_t)b * NN_ + i0 + l16) * NN_ + w * 256 + qo;
    const float* stp  = s_tgt + (size_t)bh * NN_ + w * 256 + qo;
    const short* ptb  = pt + ((size_t)b_rel * D_ + h * FO_) * NN_ + w * 256 + qo;
    const short* ptr0 = ptb + (size_t)(l16) * NN_;
    const short* ptr1 = ptb + (size_t)(16 + l16) * NN_;
    const short* ptr2 = ptb + (size_t)(32 + l16) * NN_;
    const short* ptr3 = ptb + (size_t)(48 + l16) * NN_;

    floatx4 acc[4];
#pragma unroll
    for (int nj = 0; nj < 4; ++nj)
        acc[nj] = (floatx4){0.f, 0.f, 0.f, 0.f};
    f32x2 lacc0 = (f32x2){0.f, 0.f}, lacc1 = lacc0, lacc2 = lacc0, lacc3 = lacc0;

#pragma unroll
    for (int jt = 0; jt < 8; ++jt) {              // 8 iters x 32 j per wave
        const int o = jt * 32;                    // static offset (elements)
        floatx4 stA = *(const floatx4*)(stp + o);
        floatx4 stB = *(const floatx4*)(stp + o + 4);
        floatx4 ajA = *(const floatx4*)(adjp + o);
        floatx4 ajB = *(const floatx4*)(adjp + o + 4);
        bf16x8 bf0 = *(const bf16x8*)(ptr0 + o);
        bf16x8 bf1 = *(const bf16x8*)(ptr1 + o);
        bf16x8 bf2 = *(const bf16x8*)(ptr2 + o);
        bf16x8 bf3 = *(const bf16x8*)(ptr3 + o);

        union { bf16x8 v; unsigned int u[4]; } a0;
#define SCORE2(PAIRS, PAIRA, LACC, SLOT)                                   \
        {                                                                  \
            f32x2 t = (PAIRS) + ssrc2;                                     \
            f32x2 lk = __builtin_elementwise_max(t, t * 0.2f);             \
            f32x2 u = (lk + (PAIRA)) * LOG2E;                              \
            float w0 = EXP2(u[0]);                                         \
            float w1 = EXP2(u[1]);                                         \
            LACC += (f32x2){w0, w1};                                       \
            a0.u[SLOT] = pack_bf16(w0, w1);                                \
        }
        SCORE2(((f32x2){stA[0], stA[1]}), ((f32x2){ajA[0], ajA[1]}), lacc0, 0)
        SCORE2(((f32x2){stA[2], stA[3]}), ((f32x2){ajA[2], ajA[3]}), lacc1, 1)
        SCORE2(((f32x2){stB[0], stB[1]}), ((f32x2){ajB[0], ajB[1]}), lacc2, 2)
        SCORE2(((f32x2){stB[2], stB[3]}), ((f32x2){ajB[2], ajB[3]}), lacc3, 3)
#undef SCORE2

        acc[0] = __builtin_amdgcn_mfma_f32_16x16x32_bf16(a0.v, bf0, acc[0], 0, 0, 0);
        acc[1] = __builtin_amdgcn_mfma_f32_16x16x32_bf16(a0.v, bf1, acc[1], 0, 0, 0);
        acc[2] = __builtin_amdgcn_mfma_f32_16x16x32_bf16(a0.v, bf2, acc[2], 0, 0, 0);
        acc[3] = __builtin_amdgcn_mfma_f32_16x16x32_bf16(a0.v, bf3, acc[3], 0, 0, 0);
    }

    // wave-local row-sum over quads (row = l16 in A-layout)
    f32x2 lp = lacc0 + lacc1 + lacc2 + lacc3;
    float lsum = lp[0] + lp[1];
    lsum += __shfl_xor(lsum, 16, 64);
    lsum += __shfl_xor(lsum, 32, 64);

    // stage 1: dump wave partials to LDS. C/D: row=quad*4+r, col=nj*16+l16
#pragma unroll
    for (int nj = 0; nj < 4; ++nj)
#pragma unroll
        for (int r = 0; r < 4; ++r)
            red[w][(quad * 4 + r) * RSTRIDE + nj * 16 + l16] = acc[nj][r];
    if (quad == 0)
        red[w][16 * RSTRIDE + l16] = lsum;
    __syncthreads();

    // stage 2: 512 threads reduce 16x64 elems (2 each) over 8 waves
#pragma unroll
    for (int p = 0; p < 2; ++p) {
        int e   = tid + p * 512;
        int row = e >> 6;
        int col = e & 63;
        float s = 0.f, l = 0.f;
#pragma unroll
        for (int ww = 0; ww < 8; ++ww) {
            s += red[ww][row * RSTRIDE + col];
            l += red[ww][16 * RSTRIDE + row];
        }
        float v = s / l + bias[h * FO_ + col];
        v = (v > 0.f) ? v : expm1f(v);            // elu (fp32 out)
        out[((size_t)b * NN_ + i0 + row) * D_ + h * FO_ + col] = v;
    }
}

// ---------------------------------------------------------------------------
extern "C" void kernel_launch(void* const* d_in, const int* in_sizes, int n_in,
                              void* d_out, int out_size, void* d_ws, size_t ws_size,
                              hipStream_t stream) {
    const float* x     = (const float*)d_in[0];   // (4,2048,128) fp32
    const float* adj   = (const float*)d_in[1];   // (4,2048,2048) fp32
    const float* wproj = (const float*)d_in[2];   // (256,128) fp32
    const float* ssrc  = (const float*)d_in[3];   // (4,64) fp32
    const float* stgt  = (const float*)d_in[4];   // (4,64) fp32
    const float* bias  = (const float*)d_in[5];   // (256,) fp32
    float* out = (float*)d_out;                   // (4,2048,256) fp32

    // ws layout: s_src (128 KiB) | s_tgt (128 KiB) | PT slabs (1 MiB per batch)
    const size_t SB   = (size_t)BN_ * H_ * NN_ * 4;   // 131072 B
    const size_t SLAB = (size_t)D_ * NN_ * 2;          // 1 MiB per batch
    float* s_src = (float*)d_ws;
    float* s_tgt = (float*)((char*)d_ws + SB);
    short* pt    = (short*)((char*)d_ws + 2 * SB);

    // batch-slice PT so total ws usage fits ws_size (nb constant per session)
    int nb;
    if (ws_size >= 2 * SB + 4 * SLAB) nb = 4;
    else {
        size_t avail = (ws_size > 2 * SB) ? (ws_size - 2 * SB) / SLAB : 0;
        nb = (int)avail; if (nb < 1) nb = 1; if (nb > 4) nb = 4;
    }

    for (int bb0 = 0; bb0 < BN_; bb0 += nb) {
        int cnt = (BN_ - bb0 < nb) ? (BN_ - bb0) : nb;
        proj_kernel<<<dim3(NN_ / 256, H_, cnt), 256, 0, stream>>>(
            x, wproj, ssrc, stgt, pt, s_src, s_tgt, bb0);
        attn_kernel<<<dim3(NN_ / 16, H_, cnt), 512, 0, stream>>>(
            adj, pt, s_src, s_tgt, bias, out, bb0);
    }
}